// Round 7
// baseline (318.531 us; speedup 1.0000x reference)
//
#include <hip/hip_runtime.h>

typedef unsigned int u32;
typedef unsigned short u16;
typedef __attribute__((ext_vector_type(4))) float fx4;
typedef __attribute__((ext_vector_type(8))) short s16x8;
typedef __attribute__((ext_vector_type(4))) u32 u32x4;

#define DD 128
#define KK 1024

__device__ __forceinline__ u16 f2bf(float f) {
  u32 u = __float_as_uint(f);
  return (u16)((u + 0x7FFFu + ((u >> 16) & 1u)) >> 16);
}
__device__ __forceinline__ u32 umin32(u32 a, u32 b) { return a < b ? a : b; }

// ---------------- prep: cbf fp32 -> bf16 (RTN, bit-identical to prior rounds),
// k-major cbt: [lvl(4)][ku(16)][col(1024)][8] u16 (1 MiB). 256 blocks x 64 thr.
// Also zeroes the loss slot in d_out.
extern "C" __global__ __launch_bounds__(64) void rvq_prep(
    const float* __restrict__ cbf, u16* __restrict__ cbt,
    float* __restrict__ lossout) {
  if (blockIdx.x == 0 && threadIdx.x == 0) lossout[0] = 0.f;
  const int cl = threadIdx.x >> 2, dq = threadIdx.x & 3;
  const int cw = blockIdx.x * 16 + cl;
  const int lvl = cw >> 10, colg = cw & 1023;
  const float* src = cbf + (size_t)cw * DD + dq * 32;
  u32x4* dst = (u32x4*)cbt;
#pragma unroll
  for (int k8 = 0; k8 < 4; ++k8) {
    const fx4 a = *(const fx4*)(src + k8 * 8);
    const fx4 b = *(const fx4*)(src + k8 * 8 + 4);
    u32x4 pk;
    pk.x = (u32)f2bf(a[0]) | ((u32)f2bf(a[1]) << 16);
    pk.y = (u32)f2bf(a[2]) | ((u32)f2bf(a[3]) << 16);
    pk.z = (u32)f2bf(b[0]) | ((u32)f2bf(b[1]) << 16);
    pk.w = (u32)f2bf(b[2]) | ((u32)f2bf(b[3]) << 16);
    dst[((lvl * 16 + dq * 4 + k8) * 1024) + colg] = pk;
  }
}

// ---------------- main: 512 blocks x 512 thr; block = 64 rows x 1024 cols.
// 8 waves = pair(2 row-halves of 32) x hq(4 col-16-slices). Each wave: afr[2][4]
// (32 rows) + double-buffered B stream from L2 — no K-loop barriers. 4 waves/SIMD
// (launch_bounds(512,4), LDS 68.6 KB -> 2 blocks/CU) hide B-load latency via TLP.
// Live regs ~90 < 128 cap (R6 lesson: no deeper per-wave prefetch).
extern "C" __global__ __launch_bounds__(512, 4) void rvq_main(
    const float* __restrict__ x, const float* __restrict__ cbf,
    const u16* __restrict__ cbt, float* __restrict__ yout,
    float* __restrict__ lossacc) {
  __shared__ float Rlds[64][132];  // negated residual; +4 pad
  __shared__ float xl[64][132];    // x copy (avoids HBM re-read at y-pass)
  __shared__ u32 lmin[64][4];      // [row][hq]

  const int tid = threadIdx.x;
  const int w = tid >> 6, lane = tid & 63;
  const int c = lane & 15, q = lane >> 4;
  const int hq = w & 3, pair = w >> 2;
  const int wvc = hq * 16 + c;
  const int rowbase = blockIdx.x * 64;
  const int rot = (int)((blockIdx.x >> 3) & 15);      // de-lockstep same-XCD L2 streams
  const s16x8* cbase = (const s16x8*)cbt + q * 1024;  // + lvl*16384 + s*4096 + col

  s16x8 brA[4], brB[4];
  { // prologue: issue level-0 tile-0 loads first (overlap with x init)
    const int cb0 = rot * 64 + wvc;
#pragma unroll
    for (int s5 = 0; s5 < 4; ++s5) brA[s5] = cbase[cb0 + s5 * 4096];
  }

  s16x8 afr[2][4];  // A-frags: rows pair*32 + t2*16 + c, k = s*32 + q*8 + j
#pragma unroll
  for (int t2 = 0; t2 < 2; ++t2) {
    const int row = pair * 32 + t2 * 16 + c;
    const float* xr = x + (size_t)(rowbase + row) * DD + q * 8;
#pragma unroll
    for (int s = 0; s < 4; ++s) {
      const fx4 a = *(const fx4*)(xr + s * 32);
      const fx4 b = *(const fx4*)(xr + s * 32 + 4);
      fx4 na, nb;
      s16x8 af;
#pragma unroll
      for (int j = 0; j < 4; ++j) { na[j] = -a[j]; nb[j] = -b[j]; }
#pragma unroll
      for (int j = 0; j < 4; ++j) { af[j] = (short)f2bf(na[j]); af[4 + j] = (short)f2bf(nb[j]); }
      afr[t2][s] = af;
      if (hq == 0) {
        *(fx4*)&Rlds[row][s * 32 + q * 8] = na;
        *(fx4*)&Rlds[row][s * 32 + q * 8 + 4] = nb;
        *(fx4*)&xl[row][s * 32 + q * 8] = a;
        *(fx4*)&xl[row][s * 32 + q * 8 + 4] = b;
      }
    }
  }

  u32 run[2][4];
#pragma unroll
  for (int t2 = 0; t2 < 2; ++t2)
#pragma unroll
    for (int r = 0; r < 4; ++r) run[t2][r] = 0xFFFFFFFFu;

  float lsum = 0.f;

#pragma unroll 1
  for (int lvl = 0; lvl < 4; ++lvl) {
    // acc = 0.75 - r.c ∈ (0.625,0.875) ⊂ [0.5,1): single exponent -> monotone pack
    // key = (bits(acc)<<10) + col - 2^31; ties -> lowest col (matches argmin).
#define KSTEP(CUR, NXT, CT)                                                        \
  {                                                                                \
    if ((CT) < 15 || lvl < 3) { /* prefetch tile g+1 (crosses level boundary) */   \
      const int g2 = lvl * 16 + (CT) + 1;                                          \
      const int cb2 = (g2 >> 4) * 16384 + (((g2 & 15) + rot) & 15) * 64 + wvc;     \
      _Pragma("unroll") for (int s5 = 0; s5 < 4; ++s5)                             \
          NXT[s5] = cbase[cb2 + s5 * 4096];                                        \
    }                                                                              \
    const u32 kadd = (u32)(((((CT) + rot) & 15) * 64) + wvc) - 0x80000000u;        \
    fx4 ac0 = {0.75f, 0.75f, 0.75f, 0.75f};                                        \
    fx4 ac1 = ac0;                                                                 \
    _Pragma("unroll") for (int s5 = 0; s5 < 4; ++s5) {                             \
      const s16x8 bfrag = CUR[s5];                                                 \
      ac0 = __builtin_amdgcn_mfma_f32_16x16x32_bf16(afr[0][s5], bfrag, ac0, 0, 0, 0); \
      ac1 = __builtin_amdgcn_mfma_f32_16x16x32_bf16(afr[1][s5], bfrag, ac1, 0, 0, 0); \
    }                                                                              \
    _Pragma("unroll") for (int r5 = 0; r5 < 4; ++r5) {                             \
      run[0][r5] = umin32(run[0][r5], (__float_as_uint(ac0[r5]) << 10) + kadd);    \
      run[1][r5] = umin32(run[1][r5], (__float_as_uint(ac1[r5]) << 10) + kadd);    \
    }                                                                              \
  }
    KSTEP(brA, brB, 0)  KSTEP(brB, brA, 1)  KSTEP(brA, brB, 2)  KSTEP(brB, brA, 3)
    KSTEP(brA, brB, 4)  KSTEP(brB, brA, 5)  KSTEP(brA, brB, 6)  KSTEP(brB, brA, 7)
    KSTEP(brA, brB, 8)  KSTEP(brB, brA, 9)  KSTEP(brA, brB, 10) KSTEP(brB, brA, 11)
    KSTEP(brA, brB, 12) KSTEP(brB, brA, 13) KSTEP(brA, brB, 14) KSTEP(brB, brA, 15)
#undef KSTEP

    // reduce over 16 c-lanes (C/D row lives on q*4+r, col on c)
#pragma unroll
    for (int m = 1; m < 16; m <<= 1)
#pragma unroll
      for (int t2 = 0; t2 < 2; ++t2)
#pragma unroll
        for (int r = 0; r < 4; ++r)
          run[t2][r] = umin32(run[t2][r], (u32)__shfl_xor((int)run[t2][r], m, 64));
    if (c == 0) {
#pragma unroll
      for (int t2 = 0; t2 < 2; ++t2)
#pragma unroll
        for (int r = 0; r < 4; ++r)
          lmin[pair * 32 + t2 * 16 + q * 4 + r][hq] = run[t2][r];
    }
    __syncthreads();  // lmin complete across the 4 hq waves

    // residual update, unique ownership: wave w -> rows w*8..w*8+7,
    // lane -> row w*8+(lane>>3), dims (lane&7)*16 .. +15 (exact fp32 codebook)
    const int urow = w * 8 + (lane >> 3);
    const int ud = (lane & 7) * 16;
    const u32x4 p = *(const u32x4*)&lmin[urow][0];  // 8 lanes same row: broadcast
    const u32 pm = umin32(umin32(p.x, p.y), umin32(p.z, p.w));
    const int col = (int)(pm & 1023u);
    const float* qp = cbf + ((size_t)lvl * KK + col) * DD + ud;
    float* Rr = &Rlds[urow][ud];
#pragma unroll
    for (int k4 = 0; k4 < 4; ++k4) {
      fx4 rv = *(const fx4*)(Rr + k4 * 4);
      const fx4 qv = *(const fx4*)(qp + k4 * 4);
#pragma unroll
      for (int j = 0; j < 4; ++j) { rv[j] += qv[j]; lsum = fmaf(rv[j], rv[j], lsum); }
      *(fx4*)(Rr + k4 * 4) = rv;
    }
    if (lvl < 3) {
      __syncthreads();  // all rows' new residuals visible
#pragma unroll
      for (int t2 = 0; t2 < 2; ++t2)
#pragma unroll
        for (int s = 0; s < 4; ++s) {
          const fx4 r0 = *(const fx4*)&Rlds[pair * 32 + t2 * 16 + c][s * 32 + q * 8];
          const fx4 r1 = *(const fx4*)&Rlds[pair * 32 + t2 * 16 + c][s * 32 + q * 8 + 4];
          s16x8 af;
#pragma unroll
          for (int j = 0; j < 4; ++j) { af[j] = (short)f2bf(r0[j]); af[4 + j] = (short)f2bf(r1[j]); }
          afr[t2][s] = af;
        }
#pragma unroll
      for (int t2 = 0; t2 < 2; ++t2)
#pragma unroll
        for (int r = 0; r < 4; ++r) run[t2][r] = 0xFFFFFFFFu;
    }
  }

  // ---- y epilogue: wave reads its OWN rows (same-wave LDS ordering, no barrier):
  // y = x + R_final, contiguous 512 B per half-wave, nontemporal.
#pragma unroll
  for (int pass = 0; pass < 4; ++pass) {
    const int row = w * 8 + pass * 2 + (lane >> 5);
    const int coff = (lane & 31) * 4;
    const fx4 rv = *(const fx4*)&Rlds[row][coff];
    const fx4 xv = *(const fx4*)&xl[row][coff];
    fx4 yv;
#pragma unroll
    for (int j = 0; j < 4; ++j) yv[j] = xv[j] + rv[j];
    __builtin_nontemporal_store(yv, (fx4*)(yout + (size_t)(rowbase + row) * DD + coff));
  }

#pragma unroll
  for (int m = 32; m >= 1; m >>= 1) lsum += __shfl_xor(lsum, m, 64);
  if (lane == 0) atomicAdd(lossacc, lsum * (1.25f / 4194304.f));  // 1.25/(N*D)
}

extern "C" void kernel_launch(void* const* d_in, const int* in_sizes, int n_in,
                              void* d_out, int out_size, void* d_ws, size_t ws_size,
                              hipStream_t stream) {
  const float* x = (const float*)d_in[0];     // [32768,128]
  const float* cbf = (const float*)d_in[1];   // [4,1024,128]
  float* y = (float*)d_out;
  float* lossout = y + (out_size - 1);
  u16* cbt = (u16*)d_ws;                      // 1 MiB k-major bf16 codebook

  rvq_prep<<<256, 64, 0, stream>>>(cbf, cbt, lossout);
  rvq_main<<<512, 512, 0, stream>>>(x, cbf, cbt, y, lossout);
}

// Round 8
// 198.972 us; speedup vs baseline: 1.6009x; 1.6009x over previous
//
#include <hip/hip_runtime.h>

typedef unsigned int u32;
typedef unsigned long long u64;
typedef long i64;  // 64-bit on amdgcn
typedef __attribute__((ext_vector_type(4))) float fx4;
typedef __attribute__((ext_vector_type(2))) i64 i64x2;
typedef __attribute__((ext_vector_type(4))) u32 u32x4;

#define DD 128
#define KK 1024

__device__ __forceinline__ u32 umin32(u32 a, u32 b) { return a < b ? a : b; }

// pack 8 f32 -> 8 fp8(e4m3) bytes, k-order j=0..7 (RNE, saturating)
__device__ __forceinline__ i64 pack8(fx4 a, fx4 b) {
  u32 lo = (u32)__builtin_amdgcn_cvt_pk_fp8_f32(a[0], a[1], 0, false);
  lo = (u32)__builtin_amdgcn_cvt_pk_fp8_f32(a[2], a[3], (int)lo, true);
  u32 hi = (u32)__builtin_amdgcn_cvt_pk_fp8_f32(b[0], b[1], 0, false);
  hi = (u32)__builtin_amdgcn_cvt_pk_fp8_f32(b[2], b[3], (int)hi, true);
  return (i64)(((u64)hi << 32) | lo);
}

// ---------------- prep: cbf fp32 -> fp8 e4m3 scaled x1024 (entries ~U(+-1/1024)
// -> ~U(+-1), well inside e4m3 normal range). Layout per wave-slice so rvq_main's
// lane loads are its exact B-frags:
//   cb8[lvl(4)][tile(16)][hq(4)] slice of 2048 B = [lane(=q*16+c)][32 B: s=0..3, j=0..7]
// Thread = (codeword, q): writes one contiguous 32 B chunk. Also zeroes loss slot.
extern "C" __global__ __launch_bounds__(64) void rvq_prep(
    const float* __restrict__ cbf, unsigned char* __restrict__ cb8,
    float* __restrict__ lossout) {
  if (blockIdx.x == 0 && threadIdx.x == 0) lossout[0] = 0.f;
  const int cw = blockIdx.x * 16 + (threadIdx.x >> 2);
  const int q = threadIdx.x & 3;
  const int lvl = cw >> 10, colg = cw & 1023;
  const int tile = colg >> 6, lcol = colg & 63;
  const int hq2 = lcol >> 4, cc = lcol & 15;
  const float* src = cbf + (size_t)cw * DD + q * 8;
  u32 d[8];
#pragma unroll
  for (int s = 0; s < 4; ++s) {
    const fx4 a = *(const fx4*)(src + s * 32);
    const fx4 b = *(const fx4*)(src + s * 32 + 4);
    fx4 as, bs;
#pragma unroll
    for (int j = 0; j < 4; ++j) { as[j] = a[j] * 1024.f; bs[j] = b[j] * 1024.f; }
    u32 lo = (u32)__builtin_amdgcn_cvt_pk_fp8_f32(as[0], as[1], 0, false);
    lo = (u32)__builtin_amdgcn_cvt_pk_fp8_f32(as[2], as[3], (int)lo, true);
    u32 hi = (u32)__builtin_amdgcn_cvt_pk_fp8_f32(bs[0], bs[1], 0, false);
    hi = (u32)__builtin_amdgcn_cvt_pk_fp8_f32(bs[2], bs[3], (int)hi, true);
    d[s * 2] = lo; d[s * 2 + 1] = hi;
  }
  u32* dst = (u32*)(cb8 + ((size_t)(lvl * 64 + tile * 4 + hq2) * 2048) + (q * 16 + cc) * 32);
  *(u32x4*)dst = (u32x4){d[0], d[1], d[2], d[3]};
  *(u32x4*)(dst + 4) = (u32x4){d[4], d[5], d[6], d[7]};
}

// ---------------- main: 512 blocks x 256 thr; block = 64 rows x 1024 cols.
// 4 waves; each wave holds all 64 rows as fp8 A-frags (afr[4][4], 32 VGPRs) and
// scans a 16-col slice of each 64-col tile. B streams L2->VGPR fp8 with a
// 3-buffer ring, prefetch depth 2 — no K-loop barriers, no LDS staging.
// (256,2): 256-reg budget — R4/R6/R7 lesson: any 128 budget spills this loop.
extern "C" __global__ __launch_bounds__(256, 2) void rvq_main(
    const float* __restrict__ x, const float* __restrict__ cbf,
    const unsigned char* __restrict__ cb8, float* __restrict__ yout,
    float* __restrict__ lossacc) {
  __shared__ float Rlds[64][132];  // negated residual; +4 pad (2-way = free)
  __shared__ u32 lmin[64][4];      // [row][wave]

  const int tid = threadIdx.x;
  const int wv = tid >> 6, lane = tid & 63;
  const int c = lane & 15, q = lane >> 4;
  const int rowbase = blockIdx.x * 64;
  const int rot = (int)((blockIdx.x >> 3) & 15);  // de-lockstep same-XCD L2 streams

  i64x2 br[3][2];  // ring: br[g%3] = 32 B tile slice ([0]=s0,s1  [1]=s2,s3)
  { // prologue: issue tiles g=0,1 of level 0 before anything else
#pragma unroll
    for (int g = 0; g < 2; ++g) {
      const unsigned char* p =
          cb8 + (size_t)((((g + rot) & 15) * 4 + wv) * 2048) + lane * 32;
      br[g][0] = *(const i64x2*)p;
      br[g][1] = *(const i64x2*)(p + 16);
    }
  }

  i64 afr[4][4];  // A-frags (fp8, unscaled -res): rows t*16+c, k = s*32+q*8+j
#pragma unroll
  for (int t = 0; t < 4; ++t) {
    const float* xr = x + (size_t)(rowbase + t * 16 + c) * DD + q * 8;
#pragma unroll
    for (int s = 0; s < 4; ++s) {
      const fx4 a = *(const fx4*)(xr + s * 32);
      const fx4 b = *(const fx4*)(xr + s * 32 + 4);
      fx4 na, nb;
#pragma unroll
      for (int j = 0; j < 4; ++j) { na[j] = -a[j]; nb[j] = -b[j]; }
      afr[t][s] = pack8(na, nb);
      if (t == wv) {  // wave wv owns Rlds rows wv*16..wv*16+15
        *(fx4*)&Rlds[t * 16 + c][s * 32 + q * 8] = na;
        *(fx4*)&Rlds[t * 16 + c][s * 32 + q * 8 + 4] = nb;
      }
    }
  }

  u32 run[4][4];
#pragma unroll
  for (int t = 0; t < 4; ++t)
#pragma unroll
    for (int r = 0; r < 4; ++r) run[t][r] = 0xFFFFFFFFu;

  float lsum = 0.f;

#pragma unroll 1
  for (int lvl = 0; lvl < 4; ++lvl) {
    // acc = 768 - 1024*(r.c) ∈ [512,1024) single binade; bit-span << 2^22 so
    // key = (bits(acc)<<10) + col + 2^31 is monotone; ties -> lowest col.
#define KSTEP(CT)                                                                  \
  {                                                                                \
    if ((CT) < 14 || lvl < 3) { /* prefetch tile g+2 (crosses level boundary) */   \
      const int g2 = lvl * 16 + (CT) + 2;                                          \
      const unsigned char* p =                                                     \
          cb8 + (size_t)((((g2 >> 4) * 64) + ((((g2)&15) + rot) & 15) * 4 + wv) * 2048) \
          + lane * 32;                                                             \
      br[((CT) + 2) % 3][0] = *(const i64x2*)p;                                    \
      br[((CT) + 2) % 3][1] = *(const i64x2*)(p + 16);                             \
    }                                                                              \
    const u32 kadd = (u32)(((((CT) + rot) & 15) * 64) + wv * 16 + c) + 0x80000000u;\
    fx4 ac0 = {768.f, 768.f, 768.f, 768.f};                                        \
    fx4 ac1 = ac0, ac2 = ac0, ac3 = ac0;                                           \
    _Pragma("unroll") for (int s5 = 0; s5 < 4; ++s5) {                             \
      const i64 bfrag = br[(CT) % 3][s5 >> 1][s5 & 1];                             \
      ac0 = __builtin_amdgcn_mfma_f32_16x16x32_fp8_fp8(afr[0][s5], bfrag, ac0, 0, 0, 0); \
      ac1 = __builtin_amdgcn_mfma_f32_16x16x32_fp8_fp8(afr[1][s5], bfrag, ac1, 0, 0, 0); \
      ac2 = __builtin_amdgcn_mfma_f32_16x16x32_fp8_fp8(afr[2][s5], bfrag, ac2, 0, 0, 0); \
      ac3 = __builtin_amdgcn_mfma_f32_16x16x32_fp8_fp8(afr[3][s5], bfrag, ac3, 0, 0, 0); \
    }                                                                              \
    _Pragma("unroll") for (int r5 = 0; r5 < 4; ++r5) {                             \
      run[0][r5] = umin32(run[0][r5], (__float_as_uint(ac0[r5]) << 10) + kadd);    \
      run[1][r5] = umin32(run[1][r5], (__float_as_uint(ac1[r5]) << 10) + kadd);    \
      run[2][r5] = umin32(run[2][r5], (__float_as_uint(ac2[r5]) << 10) + kadd);    \
      run[3][r5] = umin32(run[3][r5], (__float_as_uint(ac3[r5]) << 10) + kadd);    \
    }                                                                              \
  }
    KSTEP(0)  KSTEP(1)  KSTEP(2)  KSTEP(3)  KSTEP(4)  KSTEP(5)  KSTEP(6)  KSTEP(7)
    KSTEP(8)  KSTEP(9)  KSTEP(10) KSTEP(11) KSTEP(12) KSTEP(13) KSTEP(14) KSTEP(15)
#undef KSTEP

    // reduce over 16 c-lanes (C/D row lives on q*4+r, col on c)
#pragma unroll
    for (int m = 1; m < 16; m <<= 1)
#pragma unroll
      for (int t = 0; t < 4; ++t)
#pragma unroll
        for (int r = 0; r < 4; ++r)
          run[t][r] = umin32(run[t][r], (u32)__shfl_xor((int)run[t][r], m, 64));
    if (c == 0) {
#pragma unroll
      for (int t = 0; t < 4; ++t)
#pragma unroll
        for (int r = 0; r < 4; ++r)
          lmin[t * 16 + q * 4 + r][wv] = run[t][r];
    }
    __syncthreads();  // lmin complete across the 4 waves

    // residual update: wave wv owns rows wv*16+c, lane quad q owns dims q*32..+31
    // (exact fp32 codebook -> loss/residual bit-exact w.r.t. reference op order)
    const int row = wv * 16 + c;
    const u32x4 p = *(const u32x4*)&lmin[row][0];
    const u32 pm = umin32(umin32(p.x, p.y), umin32(p.z, p.w));
    const int col = (int)(pm & 1023u);
    const float* qp = cbf + ((size_t)lvl * KK + col) * DD + q * 32;
    float* Rr = &Rlds[row][q * 32];
#pragma unroll
    for (int k4 = 0; k4 < 8; ++k4) {
      fx4 rv = *(const fx4*)(Rr + k4 * 4);
      const fx4 qv = *(const fx4*)(qp + k4 * 4);
#pragma unroll
      for (int j = 0; j < 4; ++j) { rv[j] += qv[j]; lsum = fmaf(rv[j], rv[j], lsum); }
      *(fx4*)(Rr + k4 * 4) = rv;
    }
    if (lvl < 3) {
      __syncthreads();  // all rows' new residuals visible
#pragma unroll
      for (int t = 0; t < 4; ++t)
#pragma unroll
        for (int s = 0; s < 4; ++s) {
          const fx4 r0 = *(const fx4*)&Rlds[t * 16 + c][s * 32 + q * 8];
          const fx4 r1 = *(const fx4*)&Rlds[t * 16 + c][s * 32 + q * 8 + 4];
          afr[t][s] = pack8(r0, r1);
        }
#pragma unroll
      for (int t = 0; t < 4; ++t)
#pragma unroll
        for (int r = 0; r < 4; ++r) run[t][r] = 0xFFFFFFFFu;
    }
  }

  // ---- y epilogue: wave reads its OWN rows (same-wave LDS ordering, no barrier):
  // y = x + R_final, contiguous 512 B per half-wave, nontemporal (no RFO pollution).
#pragma unroll
  for (int pass = 0; pass < 8; ++pass) {
    const int row = wv * 16 + pass * 2 + (lane >> 5);
    const int coff = (lane & 31) * 4;
    const fx4 rv = *(const fx4*)&Rlds[row][coff];
    const size_t gb = (size_t)(rowbase + row) * DD + coff;
    const fx4 xv = *(const fx4*)(x + gb);
    fx4 yv;
#pragma unroll
    for (int j = 0; j < 4; ++j) yv[j] = xv[j] + rv[j];
    __builtin_nontemporal_store(yv, (fx4*)(yout + gb));
  }

#pragma unroll
  for (int m = 32; m >= 1; m >>= 1) lsum += __shfl_xor(lsum, m, 64);
  if (lane == 0) atomicAdd(lossacc, lsum * (1.25f / 4194304.f));  // 1.25/(N*D)
}

extern "C" void kernel_launch(void* const* d_in, const int* in_sizes, int n_in,
                              void* d_out, int out_size, void* d_ws, size_t ws_size,
                              hipStream_t stream) {
  const float* x = (const float*)d_in[0];     // [32768,128]
  const float* cbf = (const float*)d_in[1];   // [4,1024,128]
  float* y = (float*)d_out;
  float* lossout = y + (out_size - 1);
  unsigned char* cb8 = (unsigned char*)d_ws;  // 512 KiB fp8 codebook (x1024 scale)

  rvq_prep<<<256, 64, 0, stream>>>(cbf, cb8, lossout);
  rvq_main<<<512, 256, 0, stream>>>(x, cbf, cb8, y, lossout);
}